// Round 8
// baseline (2636.394 us; speedup 1.0000x reference)
//
#include <hip/hip_runtime.h>
#include <hip/hip_bf16.h>
#include <stdint.h>

typedef short bf16x8 __attribute__((ext_vector_type(8)));
typedef float f32x4  __attribute__((ext_vector_type(4)));
typedef unsigned int u32x4 __attribute__((ext_vector_type(4)));

static __device__ __forceinline__ unsigned short bf16_rne(float f) {
    unsigned u = __builtin_bit_cast(unsigned, f);
    unsigned r = u + 0x7fffu + ((u >> 16) & 1u);
    return (unsigned short)(r >> 16);
}
static __device__ __forceinline__ float bf16tof(unsigned short h) {
    unsigned u = ((unsigned)h) << 16;
    return __builtin_bit_cast(float, u);
}

// ---------------- K1: transpose + convert W_xh [K][N] f32 -> Wt [N][K] bf16 ---
__global__ __launch_bounds__(256) void k_transpose(const float* __restrict__ W,
                                                   unsigned short* __restrict__ Wt) {
    __shared__ float tile[64][65];
    int bx = blockIdx.x & 15, by = blockIdx.x >> 4;
    int n0 = bx * 64, k0 = by * 64;
    int tx = threadIdx.x & 63, ty = threadIdx.x >> 6;
#pragma unroll
    for (int p = 0; p < 16; ++p) {
        int r = p * 4 + ty;
        tile[r][tx] = W[(size_t)(k0 + r) * 1024 + n0 + tx];
    }
    __syncthreads();
#pragma unroll
    for (int p = 0; p < 16; ++p) {
        int r = p * 4 + ty;
        Wt[(size_t)(n0 + r) * 1024 + k0 + tx] = bf16_rne(tile[tx][r]);
    }
}

// ---------------- K2: Xp = X @ W_xh + b_h  (bf16 MFMA, 128x128x32 tiles) ------
#define LDA 80

__global__ __launch_bounds__(256) void k_xpgemm(const float* __restrict__ X,
                                                const unsigned short* __restrict__ Wt,
                                                const float* __restrict__ bh,
                                                unsigned short* __restrict__ Xp) {
    __shared__ __align__(16) unsigned char ldsA[128 * LDA];
    __shared__ __align__(16) unsigned char ldsB[128 * LDA];
    int p = blockIdx.x;
    int lo = (p & 7) * 256 + (p >> 3);
    int mt = lo >> 3, nt = lo & 7;
    int m0 = mt * 128, n0 = nt * 128;
    int tid = threadIdx.x;
    int lane = tid & 63, wid = tid >> 6;
    int wr = wid >> 1, wc = wid & 1;
    int mw = wr * 64, nw = wc * 64;
    int l15 = lane & 15, kg = lane >> 4;

    f32x4 acc[4][4] = {};
    int arow = tid >> 3, as = tid & 7;
    int brow = tid >> 2, bs = tid & 3;

    for (int kt = 0; kt < 32; ++kt) {
#pragma unroll
        for (int pp = 0; pp < 4; ++pp) {
            int r = pp * 32 + arow;
            const float4 v = *(const float4*)(X + (size_t)(m0 + r) * 1024 + kt * 32 + as * 4);
            unsigned lo32 = ((unsigned)bf16_rne(v.y) << 16) | bf16_rne(v.x);
            unsigned hi32 = ((unsigned)bf16_rne(v.w) << 16) | bf16_rne(v.z);
            *(uint2*)(ldsA + r * LDA + as * 8) = make_uint2(lo32, hi32);
        }
#pragma unroll
        for (int pp = 0; pp < 2; ++pp) {
            int r = pp * 64 + brow;
            uint4 v = *(const uint4*)(Wt + (size_t)(n0 + r) * 1024 + kt * 32 + bs * 8);
            *(uint4*)(ldsB + r * LDA + bs * 16) = v;
        }
        __syncthreads();
        bf16x8 af[4];
#pragma unroll
        for (int i = 0; i < 4; ++i)
            af[i] = *(const bf16x8*)(ldsA + (mw + 16 * i + l15) * LDA + kg * 16);
#pragma unroll
        for (int j = 0; j < 4; ++j) {
            bf16x8 bfj = *(const bf16x8*)(ldsB + (nw + 16 * j + l15) * LDA + kg * 16);
#pragma unroll
            for (int i = 0; i < 4; ++i)
                acc[i][j] = __builtin_amdgcn_mfma_f32_16x16x32_bf16(af[i], bfj, acc[i][j], 0, 0, 0);
        }
        __syncthreads();
    }
#pragma unroll
    for (int j = 0; j < 4; ++j) {
        int col = n0 + nw + 16 * j + l15;
        float bias = bh[col];
#pragma unroll
        for (int i = 0; i < 4; ++i) {
            int rb = m0 + mw + 16 * i + kg * 4;
#pragma unroll
            for (int r = 0; r < 4; ++r)
                Xp[(size_t)(rb + r) * 1024 + col] = bf16_rne(acc[i][j][r] + bias);
        }
    }
}

// ---------------- K3: scan. 32 WGs x 8 waves; LDS-shared slab; 8-flag clique. -
#define SB0 __builtin_amdgcn_sched_barrier(0)
#define WAITV0 asm volatile("s_waitcnt vmcnt(0)" ::: "memory")
#define LDT(d, a, O) asm volatile("global_load_dwordx4 %0, %1, off offset:" #O " sc1" : "=v"(d) : "v"(a) : "memory")
#define STS(a, v, O) asm volatile("global_store_short %0, %1, off offset:" #O " sc1" :: "v"(a), "v"(v) : "memory")
#define STD(a, v, O) asm volatile("global_store_dword %0, %1, off offset:" #O " sc1" :: "v"(a), "v"(v) : "memory")

__global__ __launch_bounds__(512) void k_scan(const float* __restrict__ Whh,
                                              const unsigned short* __restrict__ Xp,
                                              unsigned short* __restrict__ hbuf, // [2][64][1024] bf16
                                              unsigned int* flags,               // [32]
                                              float* __restrict__ out) {
    // LDS slab: [32 ksets][16 rows][80 B] (stride-80 = proven conflict-free)
    __shared__ __align__(16) unsigned char lds[32 * 16 * 80];

    const int bid = blockIdx.x;          // 0..31
    const int rt = bid >> 3, wct = bid & 7;
    const int b0 = rt * 16;
    const int tid = threadIdx.x;         // 0..511
    const int lane = tid & 63, wid = tid >> 6;
    const int l15 = lane & 15, kg = lane >> 4;
    const int jj = wct * 128 + wid * 16 + l15;
    const int rbase = b0 + kg * 4;

    // W_hh column-slice in registers (proven pattern; AGPR-eligible)
    bf16x8 w[32];
#pragma unroll
    for (int i = 0; i < 32; ++i) {
#pragma unroll
        for (int e = 0; e < 8; ++e)
            w[i][e] = (short)bf16_rne(Whh[(size_t)(i * 32 + kg * 8 + e) * 1024 + jj]);
    }

    const uint64_t fpoll  = (uint64_t)(flags + rt * 8 + (lane & 7));
    const uint64_t myflag = (uint64_t)(flags + bid);

    // cooperative slab load: thread tid -> row crow, col-bytes cclb (64 B each)
    const int crow = tid >> 5;           // 0..15
    const int cclb = (tid & 31) * 64;    // 0..1984
    const uint64_t crd = (uint64_t)hbuf + (uint64_t)(b0 + crow) * 2048 + cclb;
    unsigned char* ldsw = lds + (tid & 31) * 1280 + crow * 80;  // ks=(tid&31), +i*16

    const uint64_t hwr = (uint64_t)hbuf + (uint64_t)rbase * 2048 + (uint64_t)jj * 2;
    const unsigned short* xpb = Xp + (size_t)rbase * 1024 + jj;

    float hv[4];

    for (int t = 0; t < 512; ++t) {
        // ---- wave 0 polls the 8 producer-WG flags of this rt clique ----------
        if (t > 0 && wid == 0) {
            unsigned tt = (unsigned)t;
            for (;;) {
                unsigned f;
                asm volatile("global_load_dword %0, %1, off sc1\n\t"
                             "s_waitcnt vmcnt(0)"
                             : "=v"(f) : "v"(fpoll) : "memory");
                if (__all((int)(f >= tt))) break;
            }
        }
        __syncthreads();                 // releases all 8 waves; data IF-visible

        // ---- cooperative slab load (sc1) + xp loads (plain) ------------------
        u32x4 c0, c1, c2, c3;
        const uint64_t ca = crd + ((uint64_t)(t & 1) << 17);
        LDT(c0, ca, 0); LDT(c1, ca, 16); LDT(c2, ca, 32); LDT(c3, ca, 48);
        unsigned short xr[4];
#pragma unroll
        for (int r = 0; r < 4; ++r)
            xr[r] = xpb[(size_t)t * 65536 + r * 1024];
        WAITV0; SB0;
        *(u32x4*)(ldsw)      = c0; *(u32x4*)(ldsw + 16) = c1;
        *(u32x4*)(ldsw + 32) = c2; *(u32x4*)(ldsw + 48) = c3;
        __syncthreads();                 // slab ready in LDS

        // ---- MFMA from LDS (exact round-2 chain order) -----------------------
        f32x4 a0 = {0.f, 0.f, 0.f, 0.f}, a1 = {0.f, 0.f, 0.f, 0.f};
        f32x4 a2 = {0.f, 0.f, 0.f, 0.f}, a3 = {0.f, 0.f, 0.f, 0.f};
        const unsigned char* lrd = lds + l15 * 80 + kg * 16;
#pragma unroll
        for (int ks = 0; ks < 8; ++ks) {
            a0 = __builtin_amdgcn_mfma_f32_16x16x32_bf16(
                *(const bf16x8*)(lrd + (4 * ks + 0) * 1280), w[4 * ks + 0], a0, 0, 0, 0);
            a1 = __builtin_amdgcn_mfma_f32_16x16x32_bf16(
                *(const bf16x8*)(lrd + (4 * ks + 1) * 1280), w[4 * ks + 1], a1, 0, 0, 0);
            a2 = __builtin_amdgcn_mfma_f32_16x16x32_bf16(
                *(const bf16x8*)(lrd + (4 * ks + 2) * 1280), w[4 * ks + 2], a2, 0, 0, 0);
            a3 = __builtin_amdgcn_mfma_f32_16x16x32_bf16(
                *(const bf16x8*)(lrd + (4 * ks + 3) * 1280), w[4 * ks + 3], a3, 0, 0, 0);
        }
        f32x4 acc = (a0 + a1) + (a2 + a3);

        // ---- tanh ------------------------------------------------------------
        unsigned hb[4];
#pragma unroll
        for (int r = 0; r < 4; ++r) {
            float z = acc[r] + bf16tof(xr[r]);
            z = fminf(fmaxf(z, -15.f), 15.f);
            float e = __expf(2.f * z);
            float v = (e - 1.f) / (e + 1.f);
            hv[r] = v;
            hb[r] = (unsigned)bf16_rne(v);
        }

        // ---- publish: h stores -> ack -> WG barrier -> one flag --------------
        if (t < 511) {
            const uint64_t hn = hwr + ((uint64_t)((t + 1) & 1) << 17);
            STS(hn, hb[0], 0); STS(hn + 2048, hb[1], 0);
            STS(hn + 4096, hb[2], 0); STS(hn + 6144, hb[3], 0);
            WAITV0;                      // only the 4 h-stores outstanding
        }
        __syncthreads();                 // all 8 waves acked
        if (t < 511 && tid == 0)
            STD(myflag, (unsigned)(t + 1), 0);

        // ---- out stores: off the critical path (plain cached) ----------------
#pragma unroll
        for (int r = 0; r < 4; ++r)
            out[(size_t)(t * 64 + rbase + r) * 1024 + jj] = hv[r];
    }
#pragma unroll
    for (int r = 0; r < 4; ++r)
        out[(size_t)33554432 + (size_t)(rbase + r) * 1024 + jj] = hv[r];
}

// ---------------- launcher ---------------------------------------------------
extern "C" void kernel_launch(void* const* d_in, const int* in_sizes, int n_in,
                              void* d_out, int out_size, void* d_ws, size_t ws_size,
                              hipStream_t stream) {
    const float* X   = (const float*)d_in[0];
    const float* Wxh = (const float*)d_in[1];
    const float* Whh = (const float*)d_in[2];
    const float* bh  = (const float*)d_in[3];
    float* out = (float*)d_out;
    unsigned char* ws = (unsigned char*)d_ws;

    // workspace layout (bytes), high-water 69,469,184 (round-2-proven):
    //   [0)         Wt    : 2 MB   (W_xh^T bf16)
    //   [2097152)   Xp    : 64 MB  (bf16 [T*B][H])
    //   [69206016)  hbuf  : 256 KB (bf16 [2][64][1024])
    //   [69468160)  flags : 1 KB   (u32, first 32 used)
    unsigned short* Wt    = (unsigned short*)(ws);
    unsigned short* Xp    = (unsigned short*)(ws + 2097152);
    unsigned short* hbuf  = (unsigned short*)(ws + 69206016);
    unsigned int*   flags = (unsigned int*)(ws + 69468160);

    hipMemsetAsync(ws + 69206016, 0, 263168, stream);   // h(0)=0, flags=0
    hipLaunchKernelGGL(k_transpose, dim3(256), dim3(256), 0, stream, Wxh, Wt);
    hipLaunchKernelGGL(k_xpgemm, dim3(2048), dim3(256), 0, stream, X, Wt, bh, Xp);
    hipLaunchKernelGGL(k_scan, dim3(32), dim3(512), 0, stream, Whh, Xp, hbuf, flags, out);
}

// Round 10
// 2257.919 us; speedup vs baseline: 1.1676x; 1.1676x over previous
//
#include <hip/hip_runtime.h>
#include <hip/hip_bf16.h>
#include <stdint.h>

typedef short bf16x8 __attribute__((ext_vector_type(8)));
typedef float f32x4  __attribute__((ext_vector_type(4)));
typedef unsigned int u32x4 __attribute__((ext_vector_type(4)));

static __device__ __forceinline__ unsigned short bf16_rne(float f) {
    unsigned u = __builtin_bit_cast(unsigned, f);
    unsigned r = u + 0x7fffu + ((u >> 16) & 1u);
    return (unsigned short)(r >> 16);
}
static __device__ __forceinline__ float bf16tof(unsigned short h) {
    unsigned u = ((unsigned)h) << 16;
    return __builtin_bit_cast(float, u);
}

// ---------------- K1: transpose + convert W_xh [K][N] f32 -> Wt [N][K] bf16 ---
__global__ __launch_bounds__(256) void k_transpose(const float* __restrict__ W,
                                                   unsigned short* __restrict__ Wt) {
    __shared__ float tile[64][65];
    int bx = blockIdx.x & 15, by = blockIdx.x >> 4;
    int n0 = bx * 64, k0 = by * 64;
    int tx = threadIdx.x & 63, ty = threadIdx.x >> 6;
#pragma unroll
    for (int p = 0; p < 16; ++p) {
        int r = p * 4 + ty;
        tile[r][tx] = W[(size_t)(k0 + r) * 1024 + n0 + tx];
    }
    __syncthreads();
#pragma unroll
    for (int p = 0; p < 16; ++p) {
        int r = p * 4 + ty;
        Wt[(size_t)(n0 + r) * 1024 + k0 + tx] = bf16_rne(tile[tx][r]);
    }
}

// ---------------- K2: Xp = X @ W_xh + b_h  (bf16 MFMA, 128x128x32 tiles) ------
#define LDA 80

__global__ __launch_bounds__(256) void k_xpgemm(const float* __restrict__ X,
                                                const unsigned short* __restrict__ Wt,
                                                const float* __restrict__ bh,
                                                unsigned short* __restrict__ Xp) {
    __shared__ __align__(16) unsigned char ldsA[128 * LDA];
    __shared__ __align__(16) unsigned char ldsB[128 * LDA];
    int p = blockIdx.x;
    int lo = (p & 7) * 256 + (p >> 3);
    int mt = lo >> 3, nt = lo & 7;
    int m0 = mt * 128, n0 = nt * 128;
    int tid = threadIdx.x;
    int lane = tid & 63, wid = tid >> 6;
    int wr = wid >> 1, wc = wid & 1;
    int mw = wr * 64, nw = wc * 64;
    int l15 = lane & 15, kg = lane >> 4;

    f32x4 acc[4][4] = {};
    int arow = tid >> 3, as = tid & 7;
    int brow = tid >> 2, bs = tid & 3;

    for (int kt = 0; kt < 32; ++kt) {
#pragma unroll
        for (int pp = 0; pp < 4; ++pp) {
            int r = pp * 32 + arow;
            const float4 v = *(const float4*)(X + (size_t)(m0 + r) * 1024 + kt * 32 + as * 4);
            unsigned lo32 = ((unsigned)bf16_rne(v.y) << 16) | bf16_rne(v.x);
            unsigned hi32 = ((unsigned)bf16_rne(v.w) << 16) | bf16_rne(v.z);
            *(uint2*)(ldsA + r * LDA + as * 8) = make_uint2(lo32, hi32);
        }
#pragma unroll
        for (int pp = 0; pp < 2; ++pp) {
            int r = pp * 64 + brow;
            uint4 v = *(const uint4*)(Wt + (size_t)(n0 + r) * 1024 + kt * 32 + bs * 8);
            *(uint4*)(ldsB + r * LDA + bs * 16) = v;
        }
        __syncthreads();
        bf16x8 af[4];
#pragma unroll
        for (int i = 0; i < 4; ++i)
            af[i] = *(const bf16x8*)(ldsA + (mw + 16 * i + l15) * LDA + kg * 16);
#pragma unroll
        for (int j = 0; j < 4; ++j) {
            bf16x8 bfj = *(const bf16x8*)(ldsB + (nw + 16 * j + l15) * LDA + kg * 16);
#pragma unroll
            for (int i = 0; i < 4; ++i)
                acc[i][j] = __builtin_amdgcn_mfma_f32_16x16x32_bf16(af[i], bfj, acc[i][j], 0, 0, 0);
        }
        __syncthreads();
    }
#pragma unroll
    for (int j = 0; j < 4; ++j) {
        int col = n0 + nw + 16 * j + l15;
        float bias = bh[col];
#pragma unroll
        for (int i = 0; i < 4; ++i) {
            int rb = m0 + mw + 16 * i + kg * 4;
#pragma unroll
            for (int r = 0; r < 4; ++r)
                Xp[(size_t)(rb + r) * 1024 + col] = bf16_rne(acc[i][j][r] + bias);
        }
    }
}

// ---------------- K3 helpers --------------------------------------------------
#define SB0 __builtin_amdgcn_sched_barrier(0)
#define WV0 asm volatile("s_waitcnt vmcnt(0)" ::: "memory")

template<int S> static __device__ __forceinline__ void ld16s(u32x4& d, uint64_t a) {
    if constexpr (S) asm volatile("global_load_dwordx4 %0, %1, off sc0" : "=v"(d) : "v"(a) : "memory");
    else             asm volatile("global_load_dwordx4 %0, %1, off sc1" : "=v"(d) : "v"(a) : "memory");
}
template<int S> static __device__ __forceinline__ void sths(uint64_t a, unsigned v) {
    if constexpr (S) asm volatile("global_store_short %0, %1, off sc0" :: "v"(a), "v"(v) : "memory");
    else             asm volatile("global_store_short %0, %1, off sc1" :: "v"(a), "v"(v) : "memory");
}
template<int S> static __device__ __forceinline__ void stds(uint64_t a, unsigned v) {
    if constexpr (S) asm volatile("global_store_dword %0, %1, off sc0" :: "v"(a), "v"(v) : "memory");
    else             asm volatile("global_store_dword %0, %1, off sc1" :: "v"(a), "v"(v) : "memory");
}
template<int S> static __device__ __forceinline__ unsigned lddw_wait(uint64_t a) {
    unsigned f;
    if constexpr (S) asm volatile("global_load_dword %0, %1, off sc0\n\ts_waitcnt vmcnt(0)" : "=v"(f) : "v"(a) : "memory");
    else             asm volatile("global_load_dword %0, %1, off sc1\n\ts_waitcnt vmcnt(0)" : "=v"(f) : "v"(a) : "memory");
    return f;
}
static __device__ __forceinline__ void st_sys(uint64_t a, unsigned v) {
    asm volatile("global_store_dword %0, %1, off sc0 sc1" :: "v"(a), "v"(v) : "memory");
}
static __device__ __forceinline__ unsigned ld_sys_wait(uint64_t a) {
    unsigned f;
    asm volatile("global_load_dword %0, %1, off sc0 sc1\n\ts_waitcnt vmcnt(0)" : "=v"(f) : "v"(a) : "memory");
    return f;
}

// Main loop = round-8's passing body, scope-templated. S=1: sc0 (L2). S=0: sc1.
template<int S>
static __device__ __forceinline__ void scan_main(
    const float* __restrict__ Whh, const unsigned short* __restrict__ Xp,
    unsigned short* __restrict__ hbuf, unsigned* __restrict__ flags,
    float* __restrict__ out, unsigned char* lds, int chain, int mypos, int tid) {

    const int lane = tid & 63, wid = tid >> 6;
    const int l15 = lane & 15, kg = lane >> 4;
    const int jj = mypos * 128 + wid * 16 + l15;
    const int gr = chain * 16 + kg * 4;

    bf16x8 w[32];
#pragma unroll
    for (int i = 0; i < 32; ++i)
#pragma unroll
        for (int e = 0; e < 8; ++e)
            w[i][e] = (short)bf16_rne(Whh[(size_t)(i * 32 + kg * 8 + e) * 1024 + jj]);

    const uint64_t hb_c = (uint64_t)hbuf + (uint64_t)chain * 65536;
    const uint64_t fl_c = (uint64_t)flags + (uint64_t)chain * 64;
    const uint64_t fpoll = fl_c + (uint64_t)(lane & 7) * 4;
    const uint64_t myflag = fl_c + (uint64_t)mypos * 4;
    const int crow = tid >> 5;
    const uint64_t crd = hb_c + (uint64_t)crow * 2048 + (tid & 31) * 64;
    unsigned char* ldsw = lds + (tid & 31) * 1296 + crow * 80;
    const unsigned char* lrd = lds + l15 * 80 + kg * 16;
    const uint64_t hwr = hb_c + (uint64_t)(kg * 4) * 2048 + (uint64_t)jj * 2;
    const unsigned short* xpb = Xp + (size_t)gr * 1024 + jj;

    float hv[4];

    for (int t = 0; t < 512; ++t) {
        if (t > 0 && wid == 0) {
            unsigned tt = (unsigned)t;
            for (;;) {
                unsigned f = lddw_wait<S>(fpoll);
                if (__all(f >= tt)) break;
            }
        }
        __syncthreads();

        u32x4 c0, c1, c2, c3;
        const uint64_t ca = crd + (uint64_t)(t & 1) * 32768;
        ld16s<S>(c0, ca); ld16s<S>(c1, ca + 16); ld16s<S>(c2, ca + 32); ld16s<S>(c3, ca + 48);
        unsigned short xr[4];
#pragma unroll
        for (int r = 0; r < 4; ++r)
            xr[r] = xpb[(size_t)t * 65536 + r * 1024];
        WV0; SB0;
        *(u32x4*)(ldsw)      = c0; *(u32x4*)(ldsw + 16) = c1;
        *(u32x4*)(ldsw + 32) = c2; *(u32x4*)(ldsw + 48) = c3;
        __syncthreads();

        f32x4 a0 = {0.f, 0.f, 0.f, 0.f}, a1 = {0.f, 0.f, 0.f, 0.f};
        f32x4 a2 = {0.f, 0.f, 0.f, 0.f}, a3 = {0.f, 0.f, 0.f, 0.f};
#pragma unroll
        for (int ks = 0; ks < 8; ++ks) {
            a0 = __builtin_amdgcn_mfma_f32_16x16x32_bf16(
                *(const bf16x8*)(lrd + (4 * ks + 0) * 1296), w[4 * ks + 0], a0, 0, 0, 0);
            a1 = __builtin_amdgcn_mfma_f32_16x16x32_bf16(
                *(const bf16x8*)(lrd + (4 * ks + 1) * 1296), w[4 * ks + 1], a1, 0, 0, 0);
            a2 = __builtin_amdgcn_mfma_f32_16x16x32_bf16(
                *(const bf16x8*)(lrd + (4 * ks + 2) * 1296), w[4 * ks + 2], a2, 0, 0, 0);
            a3 = __builtin_amdgcn_mfma_f32_16x16x32_bf16(
                *(const bf16x8*)(lrd + (4 * ks + 3) * 1296), w[4 * ks + 3], a3, 0, 0, 0);
        }
        f32x4 acc = (a0 + a1) + (a2 + a3);

        unsigned hb4[4];
#pragma unroll
        for (int r = 0; r < 4; ++r) {
            float z = acc[r] + bf16tof(xr[r]);
            z = fminf(fmaxf(z, -15.f), 15.f);
            float e = __expf(2.f * z);
            float v = (e - 1.f) / (e + 1.f);
            hv[r] = v;
            hb4[r] = (unsigned)bf16_rne(v);
        }

        if (t < 511) {
            const uint64_t hn = hwr + (uint64_t)((t + 1) & 1) * 32768;
            sths<S>(hn, hb4[0]); sths<S>(hn + 2048, hb4[1]);
            sths<S>(hn + 4096, hb4[2]); sths<S>(hn + 6144, hb4[3]);
            WV0;
        }
        __syncthreads();
        if (t < 511 && tid == 0)
            stds<S>(myflag, (unsigned)(t + 1));

#pragma unroll
        for (int r = 0; r < 4; ++r)
            out[(size_t)(t * 64 + gr + r) * 1024 + jj] = hv[r];
    }
#pragma unroll
    for (int r = 0; r < 4; ++r)
        out[(size_t)33554432 + (size_t)(gr + r) * 1024 + jj] = hv[r];
}

// ---------------- K3: verified-fast scan --------------------------------------
__global__ __launch_bounds__(512) void k_scan(const float* __restrict__ Whh,
                                              const unsigned short* __restrict__ Xp,
                                              unsigned short* __restrict__ hbuf,
                                              unsigned int* flags,   // [4][16] u32 + nonce[4] @ +960B
                                              unsigned int* aux,     // 6 x 32 u32 (xcc,rdy1,rdy2,verd,rdy3,test)
                                              float* __restrict__ out) {
    __shared__ __align__(16) unsigned char lds[32 * 1296];
    const int wgid = blockIdx.x, tid = threadIdx.x;
    const int lane = tid & 63, wid = tid >> 6;
    const int c8 = wgid & 7;
    if (c8 >= 4) return;                       // 32 workers
    const int chain = c8, mypos = wgid >> 3;   // chain's 8 WGs all == chain (mod 8)
    const int windex = mypos * 4 + chain;      // 0..31
    const uint64_t A = (uint64_t)aux;
    const uint64_t F = (uint64_t)flags;

    // ---- P0: nonce + XCC publish (system scope, proven) ----------------------
    unsigned xcc;
    asm volatile("s_getreg_b32 %0, hwreg(20, 0, 32)" : "=s"(xcc));
    xcc &= 7u;
    if (tid == 0) {
        if (mypos == 0) {
            uint64_t tm;
            asm volatile("s_memtime %0" : "=s"(tm));
            st_sys(F + 960 + (uint64_t)chain * 4, ((unsigned)tm ^ (unsigned)(tm >> 32)) | 1u);
        }
        st_sys(A + (uint64_t)windex * 4, xcc);
        WV0;
        st_sys(A + 128 + (uint64_t)windex * 4, 1u);
    }
    {   // poll chain's 8 rdy1 (unbounded, system scope — deadlock-free)
        uint64_t p = A + 128 + (uint64_t)(chain + 4 * (lane & 7)) * 4;
        for (;;) { unsigned f = ld_sys_wait(p); if (__all(f == 1u)) break; }
    }
    unsigned mapok;
    {
        unsigned x = ld_sys_wait(A + (uint64_t)(chain + 4 * (lane & 7)) * 4);
        unsigned x0 = (unsigned)__shfl((int)x, 0);
        mapok = __all(x == x0) ? 1u : 0u;
    }
    const unsigned nonce = ld_sys_wait(F + 960 + (uint64_t)chain * 4);

    // ---- P1: sc0-zero my slab slice/flag/test (insurance), rendezvous2 -------
    const int l15 = lane & 15, kg = lane >> 4;
    const uint64_t hwr0 = (uint64_t)hbuf + (uint64_t)chain * 65536 +
                          (uint64_t)(kg * 4) * 2048 +
                          (uint64_t)(mypos * 128 + wid * 16 + l15) * 2;
    if (mapok) {
#pragma unroll
        for (int par = 0; par < 2; ++par)
#pragma unroll
            for (int r = 0; r < 4; ++r)
                sths<1>(hwr0 + (uint64_t)par * 32768 + (uint64_t)r * 2048, 0u);
        if (tid == 0) {
            stds<1>(F + (uint64_t)chain * 64 + (uint64_t)mypos * 4, 0u);
            stds<1>(A + 640 + (uint64_t)windex * 4, 0u);
        }
        WV0;
    }
    __syncthreads();
    if (tid == 0) st_sys(A + 256 + (uint64_t)windex * 4, 1u);
    {
        uint64_t p = A + 256 + (uint64_t)(chain + 4 * (lane & 7)) * 4;
        for (;;) { unsigned f = ld_sys_wait(p); if (__all(f == 1u)) break; }
    }

    // ---- P2: bounded sc0 ping-pong (proves L2-scope visibility) --------------
    unsigned localok = mapok;
    if (mapok) {
        if (tid == 0) stds<1>(A + 640 + (uint64_t)windex * 4, nonce ^ (unsigned)windex);
        uint64_t p = A + 640 + (uint64_t)(chain + 4 * (lane & 7)) * 4;
        unsigned expv = nonce ^ (unsigned)(chain + 4 * (lane & 7));
        int ok = 0;
        for (int it = 0; it < 5000; ++it) {
            unsigned f = lddw_wait<1>(p);
            if (__all(f == expv)) { ok = 1; break; }
        }
        localok = (unsigned)ok;
    }
    if (tid == 0) {
        st_sys(A + 384 + (uint64_t)windex * 4, localok ? 1u : 2u);
        WV0;
        st_sys(A + 512 + (uint64_t)windex * 4, 1u);
    }
    {
        uint64_t p = A + 512 + (uint64_t)(chain + 4 * (lane & 7)) * 4;
        for (;;) { unsigned f = ld_sys_wait(p); if (__all(f == 1u)) break; }
    }
    unsigned v = ld_sys_wait(A + 384 + (uint64_t)(chain + 4 * (lane & 7)) * 4);
    const int FAST = __all(v == 1u) ? 1 : 0;
    __syncthreads();

    // ---- main loop (FAST: sc0/L2 hops; SAFE: round-8-proven sc1) -------------
    if (FAST) scan_main<1>(Whh, Xp, hbuf, flags, out, lds, chain, mypos, tid);
    else      scan_main<0>(Whh, Xp, hbuf, flags, out, lds, chain, mypos, tid);
}

// ---------------- launcher ---------------------------------------------------
extern "C" void kernel_launch(void* const* d_in, const int* in_sizes, int n_in,
                              void* d_out, int out_size, void* d_ws, size_t ws_size,
                              hipStream_t stream) {
    const float* X   = (const float*)d_in[0];
    const float* Wxh = (const float*)d_in[1];
    const float* Whh = (const float*)d_in[2];
    const float* bh  = (const float*)d_in[3];
    float* out = (float*)d_out;
    unsigned char* ws = (unsigned char*)d_ws;

    // workspace layout (bytes), high-water 69,469,184 (round-2-proven):
    //   [0)         Wt    : 2 MB    (W_xh^T bf16)
    //   [2097152)   Xp    : 64 MB   (bf16 [T*B][H])
    //   [69206016)  hbuf  : 256 KB  (bf16 [4 chain][2 par][16][1024])
    //   [69468160)  flags : 256 B ([4][16] u32) + nonce[4] @ +960; 1 KB total
    //   [69468416)  aux   : 768 B  (xcc/rdy1/rdy2/verd/rdy3/test, 6 x 128 B)
    unsigned short* Wt    = (unsigned short*)(ws);
    unsigned short* Xp    = (unsigned short*)(ws + 2097152);
    unsigned short* hbuf  = (unsigned short*)(ws + 69206016);
    unsigned int*   flags = (unsigned int*)(ws + 69468160);
    unsigned int*   aux   = (unsigned int*)(ws + 69468416);

    hipMemsetAsync(ws + 69206016, 0, 263168, stream);   // hbuf + flags + aux
    hipLaunchKernelGGL(k_transpose, dim3(256), dim3(256), 0, stream, Wxh, Wt);
    hipLaunchKernelGGL(k_xpgemm, dim3(2048), dim3(256), 0, stream, X, Wt, bh, Xp);
    hipLaunchKernelGGL(k_scan, dim3(64), dim3(512), 0, stream, Whh, Xp, hbuf, flags, aux, out);
}

// Round 11
// 2098.578 us; speedup vs baseline: 1.2563x; 1.0759x over previous
//
#include <hip/hip_runtime.h>
#include <hip/hip_bf16.h>
#include <stdint.h>

typedef short bf16x8 __attribute__((ext_vector_type(8)));
typedef float f32x4  __attribute__((ext_vector_type(4)));
typedef unsigned int u32x4 __attribute__((ext_vector_type(4)));
typedef unsigned int u32x2 __attribute__((ext_vector_type(2)));

static __device__ __forceinline__ unsigned short bf16_rne(float f) {
    unsigned u = __builtin_bit_cast(unsigned, f);
    unsigned r = u + 0x7fffu + ((u >> 16) & 1u);
    return (unsigned short)(r >> 16);
}
static __device__ __forceinline__ float bf16tof(unsigned short h) {
    unsigned u = ((unsigned)h) << 16;
    return __builtin_bit_cast(float, u);
}

// ---------------- K1: transpose + convert W_xh [K][N] f32 -> Wt [N][K] bf16 ---
__global__ __launch_bounds__(256) void k_transpose(const float* __restrict__ W,
                                                   unsigned short* __restrict__ Wt) {
    __shared__ float tile[64][65];
    int bx = blockIdx.x & 15, by = blockIdx.x >> 4;
    int n0 = bx * 64, k0 = by * 64;
    int tx = threadIdx.x & 63, ty = threadIdx.x >> 6;
#pragma unroll
    for (int p = 0; p < 16; ++p) {
        int r = p * 4 + ty;
        tile[r][tx] = W[(size_t)(k0 + r) * 1024 + n0 + tx];
    }
    __syncthreads();
#pragma unroll
    for (int p = 0; p < 16; ++p) {
        int r = p * 4 + ty;
        Wt[(size_t)(n0 + r) * 1024 + k0 + tx] = bf16_rne(tile[tx][r]);
    }
}

// ---------------- K2: Xp = X @ W_xh + b_h  (bf16 MFMA, 128x128x32 tiles) ------
#define LDA 80

__global__ __launch_bounds__(256) void k_xpgemm(const float* __restrict__ X,
                                                const unsigned short* __restrict__ Wt,
                                                const float* __restrict__ bh,
                                                unsigned short* __restrict__ Xp) {
    __shared__ __align__(16) unsigned char ldsA[128 * LDA];
    __shared__ __align__(16) unsigned char ldsB[128 * LDA];
    int p = blockIdx.x;
    int lo = (p & 7) * 256 + (p >> 3);
    int mt = lo >> 3, nt = lo & 7;
    int m0 = mt * 128, n0 = nt * 128;
    int tid = threadIdx.x;
    int lane = tid & 63, wid = tid >> 6;
    int wr = wid >> 1, wc = wid & 1;
    int mw = wr * 64, nw = wc * 64;
    int l15 = lane & 15, kg = lane >> 4;

    f32x4 acc[4][4] = {};
    int arow = tid >> 3, as = tid & 7;
    int brow = tid >> 2, bs = tid & 3;

    for (int kt = 0; kt < 32; ++kt) {
#pragma unroll
        for (int pp = 0; pp < 4; ++pp) {
            int r = pp * 32 + arow;
            const float4 v = *(const float4*)(X + (size_t)(m0 + r) * 1024 + kt * 32 + as * 4);
            unsigned lo32 = ((unsigned)bf16_rne(v.y) << 16) | bf16_rne(v.x);
            unsigned hi32 = ((unsigned)bf16_rne(v.w) << 16) | bf16_rne(v.z);
            *(uint2*)(ldsA + r * LDA + as * 8) = make_uint2(lo32, hi32);
        }
#pragma unroll
        for (int pp = 0; pp < 2; ++pp) {
            int r = pp * 64 + brow;
            uint4 v = *(const uint4*)(Wt + (size_t)(n0 + r) * 1024 + kt * 32 + bs * 8);
            *(uint4*)(ldsB + r * LDA + bs * 16) = v;
        }
        __syncthreads();
        bf16x8 af[4];
#pragma unroll
        for (int i = 0; i < 4; ++i)
            af[i] = *(const bf16x8*)(ldsA + (mw + 16 * i + l15) * LDA + kg * 16);
#pragma unroll
        for (int j = 0; j < 4; ++j) {
            bf16x8 bfj = *(const bf16x8*)(ldsB + (nw + 16 * j + l15) * LDA + kg * 16);
#pragma unroll
            for (int i = 0; i < 4; ++i)
                acc[i][j] = __builtin_amdgcn_mfma_f32_16x16x32_bf16(af[i], bfj, acc[i][j], 0, 0, 0);
        }
        __syncthreads();
    }
#pragma unroll
    for (int j = 0; j < 4; ++j) {
        int col = n0 + nw + 16 * j + l15;
        float bias = bh[col];
#pragma unroll
        for (int i = 0; i < 4; ++i) {
            int rb = m0 + mw + 16 * i + kg * 4;
#pragma unroll
            for (int r = 0; r < 4; ++r)
                Xp[(size_t)(rb + r) * 1024 + col] = bf16_rne(acc[i][j][r] + bias);
        }
    }
}

// ---------------- K3 helpers --------------------------------------------------
#define SB0 __builtin_amdgcn_sched_barrier(0)
#define WV0 asm volatile("s_waitcnt vmcnt(0)" ::: "memory")

template<int S> static __device__ __forceinline__ void ld16s(u32x4& d, uint64_t a) {
    if constexpr (S) asm volatile("global_load_dwordx4 %0, %1, off sc0" : "=v"(d) : "v"(a) : "memory");
    else             asm volatile("global_load_dwordx4 %0, %1, off sc1" : "=v"(d) : "v"(a) : "memory");
}
template<int S> static __device__ __forceinline__ void st8s(uint64_t a, u32x2 v) {
    if constexpr (S) asm volatile("global_store_dwordx2 %0, %1, off sc0" :: "v"(a), "v"(v) : "memory");
    else             asm volatile("global_store_dwordx2 %0, %1, off sc1" :: "v"(a), "v"(v) : "memory");
}
template<int S> static __device__ __forceinline__ void stds(uint64_t a, unsigned v) {
    if constexpr (S) asm volatile("global_store_dword %0, %1, off sc0" :: "v"(a), "v"(v) : "memory");
    else             asm volatile("global_store_dword %0, %1, off sc1" :: "v"(a), "v"(v) : "memory");
}
template<int S> static __device__ __forceinline__ unsigned lddw_wait(uint64_t a) {
    unsigned f;
    if constexpr (S) asm volatile("global_load_dword %0, %1, off sc0\n\ts_waitcnt vmcnt(0)" : "=v"(f) : "v"(a) : "memory");
    else             asm volatile("global_load_dword %0, %1, off sc1\n\ts_waitcnt vmcnt(0)" : "=v"(f) : "v"(a) : "memory");
    return f;
}
static __device__ __forceinline__ void st_sys(uint64_t a, unsigned v) {
    asm volatile("global_store_dword %0, %1, off sc0 sc1" :: "v"(a), "v"(v) : "memory");
}
static __device__ __forceinline__ unsigned ld_sys_wait(uint64_t a) {
    unsigned f;
    asm volatile("global_load_dword %0, %1, off sc0 sc1\n\ts_waitcnt vmcnt(0)" : "=v"(f) : "v"(a) : "memory");
    return f;
}

// Transposed-MFMA main loop. Lane owns 4 consecutive j (cols), one batch row.
template<int S>
static __device__ __forceinline__ void scan_main(
    const float* __restrict__ Whh, const unsigned short* __restrict__ Xp,
    unsigned short* __restrict__ hbuf, unsigned* __restrict__ flags,
    float* __restrict__ out, unsigned char* lds, int chain, int mypos, int tid) {

    const int lane = tid & 63, wid = tid >> 6;
    const int l15 = lane & 15, kg = lane >> 4;
    const int jt = mypos * 128 + wid * 16;        // wave's 16-col tile base
    const int b  = chain * 16 + l15;              // lane's batch row (output side)
    const int jl = jt + kg * 4;                   // lane's first output column

    // W^T fragment: w[i][e] = W[k=i*32+kg*8+e][jt+l15] — address identical to
    // the proven layout; only the mfma operand ORDER changes below.
    bf16x8 w[32];
#pragma unroll
    for (int i = 0; i < 32; ++i)
#pragma unroll
        for (int e = 0; e < 8; ++e)
            w[i][e] = (short)bf16_rne(Whh[(size_t)(i * 32 + kg * 8 + e) * 1024 + jt + l15]);

    const uint64_t hb_c = (uint64_t)hbuf + (uint64_t)chain * 65536;
    const uint64_t fl_c = (uint64_t)flags + (uint64_t)chain * 64;
    const uint64_t fpoll = fl_c + (uint64_t)wid * 4;     // wave w polls producer w
    const uint64_t myflag = fl_c + (uint64_t)mypos * 4;

    // consumer: wave wid stages producer wid's slice (16 rows x 256B)
    const uint64_t crd = hb_c + (uint64_t)(lane >> 2) * 2048 + wid * 256 + (lane & 3) * 64;
    unsigned char* ldsw = lds + (lane >> 2) * 2064 + wid * 256 + (lane & 3) * 64;
    const unsigned char* lrd = lds + l15 * 2064 + kg * 16;

    const uint64_t hwr  = hb_c + (uint64_t)l15 * 2048 + (uint64_t)jl * 2;   // 8B store
    const uint64_t xpb  = (uint64_t)Xp + ((uint64_t)b * 1024 + jl) * 2;     // 8B load
    const uint64_t outb = (uint64_t)out + ((uint64_t)b * 1024 + jl) * 4;    // 16B store

    u32x2 xr;
    asm volatile("global_load_dwordx2 %0, %1, off" : "=v"(xr) : "v"(xpb) : "memory");

    f32x4 hv = {0.f, 0.f, 0.f, 0.f};

    for (int t = 0; t < 512; ++t) {
        if (t > 0) {
            unsigned tt = (unsigned)t;
            for (;;) { unsigned f = lddw_wait<S>(fpoll); if (__all(f >= tt)) break; }
        }
        u32x4 c0, c1, c2, c3;
        const uint64_t ca = crd + (uint64_t)(t & 1) * 32768;
        ld16s<S>(c0, ca); ld16s<S>(c1, ca + 16); ld16s<S>(c2, ca + 32); ld16s<S>(c3, ca + 48);
        WV0; SB0;                          // slice + prior out/xp retired
        *(u32x4*)(ldsw)      = c0; *(u32x4*)(ldsw + 16) = c1;
        *(u32x4*)(ldsw + 32) = c2; *(u32x4*)(ldsw + 48) = c3;
        __syncthreads();

        // transposed MFMA: A = W^T frag, B = h frag  -> D[j][b]
        f32x4 a0 = {0.f, 0.f, 0.f, 0.f}, a1 = {0.f, 0.f, 0.f, 0.f};
        f32x4 a2 = {0.f, 0.f, 0.f, 0.f}, a3 = {0.f, 0.f, 0.f, 0.f};
#pragma unroll
        for (int ks = 0; ks < 8; ++ks) {
            a0 = __builtin_amdgcn_mfma_f32_16x16x32_bf16(
                w[4 * ks + 0], *(const bf16x8*)(lrd + (4 * ks + 0) * 64), a0, 0, 0, 0);
            a1 = __builtin_amdgcn_mfma_f32_16x16x32_bf16(
                w[4 * ks + 1], *(const bf16x8*)(lrd + (4 * ks + 1) * 64), a1, 0, 0, 0);
            a2 = __builtin_amdgcn_mfma_f32_16x16x32_bf16(
                w[4 * ks + 2], *(const bf16x8*)(lrd + (4 * ks + 2) * 64), a2, 0, 0, 0);
            a3 = __builtin_amdgcn_mfma_f32_16x16x32_bf16(
                w[4 * ks + 3], *(const bf16x8*)(lrd + (4 * ks + 3) * 64), a3, 0, 0, 0);
        }
        f32x4 acc = (a0 + a1) + (a2 + a3);

        float xpf[4] = { bf16tof((unsigned short)(xr[0] & 0xffffu)),
                         bf16tof((unsigned short)(xr[0] >> 16)),
                         bf16tof((unsigned short)(xr[1] & 0xffffu)),
                         bf16tof((unsigned short)(xr[1] >> 16)) };
        unsigned hb16[4];
#pragma unroll
        for (int r = 0; r < 4; ++r) {
            float z = acc[r] + xpf[r];
            z = fminf(fmaxf(z, -15.f), 15.f);
            float e = __expf(2.f * z);
            float v = (e - 1.f) / (e + 1.f);
            hv[r] = v;
            hb16[r] = (unsigned)bf16_rne(v);
        }

        if (t < 511) {
            u32x2 hh = { hb16[0] | (hb16[1] << 16), hb16[2] | (hb16[3] << 16) };
            st8s<S>(hwr + (uint64_t)((t + 1) & 1) * 32768, hh);
            WV0;                           // only the 8B h-store outstanding
        }
        __syncthreads();
        if (t < 511 && tid == 0) stds<S>(myflag, (unsigned)(t + 1));

        if (t < 511)                       // xp prefetch: retires during next poll
            asm volatile("global_load_dwordx2 %0, %1, off"
                         : "=v"(xr) : "v"(xpb + (uint64_t)(t + 1) * 131072) : "memory");
        asm volatile("global_store_dwordx4 %0, %1, off"
                     :: "v"(outb + (uint64_t)t * 262144), "v"(hv) : "memory");
    }
    asm volatile("global_store_dwordx4 %0, %1, off"
                 :: "v"((uint64_t)out + ((uint64_t)33554432 + (uint64_t)b * 1024 + jl) * 4),
                    "v"(hv) : "memory");
}

// ---------------- K3: verified-fast scan (round-10-proven consensus) ----------
__global__ __launch_bounds__(512) void k_scan(const float* __restrict__ Whh,
                                              const unsigned short* __restrict__ Xp,
                                              unsigned short* __restrict__ hbuf,
                                              unsigned int* flags,   // [4][16] u32 + nonce[4] @ +960B
                                              unsigned int* aux,     // 6 x 32 u32
                                              float* __restrict__ out) {
    __shared__ __align__(16) unsigned char lds[16 * 2064];
    const int wgid = blockIdx.x, tid = threadIdx.x;
    const int lane = tid & 63, wid = tid >> 6;
    const int c8 = wgid & 7;
    if (c8 >= 4) return;
    const int chain = c8, mypos = wgid >> 3;
    const int windex = mypos * 4 + chain;
    const uint64_t A = (uint64_t)aux;
    const uint64_t F = (uint64_t)flags;

    // ---- P0: nonce + XCC publish (system scope, proven) ----------------------
    unsigned xcc;
    asm volatile("s_getreg_b32 %0, hwreg(20, 0, 32)" : "=s"(xcc));
    xcc &= 7u;
    if (tid == 0) {
        if (mypos == 0) {
            uint64_t tm;
            asm volatile("s_memtime %0" : "=s"(tm));
            st_sys(F + 960 + (uint64_t)chain * 4, ((unsigned)tm ^ (unsigned)(tm >> 32)) | 1u);
        }
        st_sys(A + (uint64_t)windex * 4, xcc);
        WV0;
        st_sys(A + 128 + (uint64_t)windex * 4, 1u);
    }
    {
        uint64_t p = A + 128 + (uint64_t)(chain + 4 * (lane & 7)) * 4;
        for (;;) { unsigned f = ld_sys_wait(p); if (__all(f == 1u)) break; }
    }
    unsigned mapok;
    {
        unsigned x = ld_sys_wait(A + (uint64_t)(chain + 4 * (lane & 7)) * 4);
        unsigned x0 = (unsigned)__shfl((int)x, 0);
        mapok = __all(x == x0) ? 1u : 0u;
    }
    const unsigned nonce = ld_sys_wait(F + 960 + (uint64_t)chain * 4);

    // ---- P1: sc0-zero my slab cells/flag/test (insurance), rendezvous2 -------
    const int l15 = lane & 15, kg = lane >> 4;
    const uint64_t hwr0 = (uint64_t)hbuf + (uint64_t)chain * 65536 +
                          (uint64_t)l15 * 2048 +
                          (uint64_t)(mypos * 128 + wid * 16 + kg * 4) * 2;
    if (mapok) {
#pragma unroll
        for (int par = 0; par < 2; ++par) {
            stds<1>(hwr0 + (uint64_t)par * 32768, 0u);
            stds<1>(hwr0 + (uint64_t)par * 32768 + 4, 0u);
        }
        if (tid == 0) {
            stds<1>(F + (uint64_t)chain * 64 + (uint64_t)mypos * 4, 0u);
            stds<1>(A + 640 + (uint64_t)windex * 4, 0u);
        }
        WV0;
    }
    __syncthreads();
    if (tid == 0) st_sys(A + 256 + (uint64_t)windex * 4, 1u);
    {
        uint64_t p = A + 256 + (uint64_t)(chain + 4 * (lane & 7)) * 4;
        for (;;) { unsigned f = ld_sys_wait(p); if (__all(f == 1u)) break; }
    }

    // ---- P2: bounded sc0 ping-pong (proves L2-scope visibility) --------------
    unsigned localok = mapok;
    if (mapok) {
        if (tid == 0) stds<1>(A + 640 + (uint64_t)windex * 4, nonce ^ (unsigned)windex);
        uint64_t p = A + 640 + (uint64_t)(chain + 4 * (lane & 7)) * 4;
        unsigned expv = nonce ^ (unsigned)(chain + 4 * (lane & 7));
        int ok = 0;
        for (int it = 0; it < 5000; ++it) {
            unsigned f = lddw_wait<1>(p);
            if (__all(f == expv)) { ok = 1; break; }
        }
        localok = (unsigned)ok;
    }
    if (tid == 0) {
        st_sys(A + 384 + (uint64_t)windex * 4, localok ? 1u : 2u);
        WV0;
        st_sys(A + 512 + (uint64_t)windex * 4, 1u);
    }
    {
        uint64_t p = A + 512 + (uint64_t)(chain + 4 * (lane & 7)) * 4;
        for (;;) { unsigned f = ld_sys_wait(p); if (__all(f == 1u)) break; }
    }
    unsigned v = ld_sys_wait(A + 384 + (uint64_t)(chain + 4 * (lane & 7)) * 4);
    const int FAST = __all(v == 1u) ? 1 : 0;
    __syncthreads();

    if (FAST) scan_main<1>(Whh, Xp, hbuf, flags, out, lds, chain, mypos, tid);
    else      scan_main<0>(Whh, Xp, hbuf, flags, out, lds, chain, mypos, tid);
}

// ---------------- launcher ---------------------------------------------------
extern "C" void kernel_launch(void* const* d_in, const int* in_sizes, int n_in,
                              void* d_out, int out_size, void* d_ws, size_t ws_size,
                              hipStream_t stream) {
    const float* X   = (const float*)d_in[0];
    const float* Wxh = (const float*)d_in[1];
    const float* Whh = (const float*)d_in[2];
    const float* bh  = (const float*)d_in[3];
    float* out = (float*)d_out;
    unsigned char* ws = (unsigned char*)d_ws;

    // workspace layout (bytes), high-water 69,469,184 (round-2-proven):
    //   [0)         Wt    : 2 MB    (W_xh^T bf16)
    //   [2097152)   Xp    : 64 MB   (bf16 [T*B][H])
    //   [69206016)  hbuf  : 256 KB  (bf16 [4 chain][2 par][16 b][1024 k])
    //   [69468160)  flags : 1 KB    ([4][16] u32 + nonce[4] @ +960)
    //   [69468416)  aux   : 768 B
    unsigned short* Wt    = (unsigned short*)(ws);
    unsigned short* Xp    = (unsigned short*)(ws + 2097152);
    unsigned short* hbuf  = (unsigned short*)(ws + 69206016);
    unsigned int*   flags = (unsigned int*)(ws + 69468160);
    unsigned int*   aux   = (unsigned int*)(ws + 69468416);

    hipMemsetAsync(ws + 69206016, 0, 263168, stream);   // hbuf + flags + aux
    hipLaunchKernelGGL(k_transpose, dim3(256), dim3(256), 0, stream, Wxh, Wt);
    hipLaunchKernelGGL(k_xpgemm, dim3(2048), dim3(256), 0, stream, X, Wt, bh, Xp);
    hipLaunchKernelGGL(k_scan, dim3(64), dim3(512), 0, stream, Whh, Xp, hbuf, flags, aux, out);
}